// Round 1
// baseline (40.970 us; speedup 1.0000x reference)
//
#include <hip/hip_runtime.h>
#include <math.h>

// NonLinearLayer: piecewise-quadratic CDF flow on a geometric mesh.
// x:(N,16) f32, pdj:(N,1), sldj:(N,1), log_p:(63,16), mesh_norm:(65,), elmt_size:(64,)
// out = concat(x_out (N*16), pdj_out (N), sldj_out (N))

namespace {
constexpr int DIM = 16;    // INPUT_DIM
constexpr int ME  = 64;    // NUM_ELMT
constexpr float BOUNDF = 50.0f;
// mesh constants (MESH_RATIO=1.2, BOUND=50):
//   1.2^32 = 341.8218917..., one_step = 10/(1.2^32-1) = 0.029340416...
//   K1 = 0.2/one_step = 6.8164378..., 1/log2(1.2) = 3.8017840...
constexpr float K1        = 6.8164378f;
constexpr float INV_L2R   = 3.8017840f;
}

__device__ __forceinline__ int imin(int a, int b) { return a < b ? a : b; }
__device__ __forceinline__ int imax(int a, int b) { return a > b ? a : b; }

__global__ __launch_bounds__(256) void nll_kernel(
    const float* __restrict__ x,
    const float* __restrict__ pdj,
    const float* __restrict__ sldj,
    const float* __restrict__ log_p,
    const float* __restrict__ mesh_norm,
    const float* __restrict__ elmt_size,
    float* __restrict__ out,
    int npts, int nquads)
{
  __shared__ float  s_mesh[ME + 1];
  __shared__ float4 s_coef[ME * 17];   // [bin][dim] padded stride 17 -> bank group (bin+dim)&7

  const int tid = threadIdx.x;
  if (tid <= ME) s_mesh[tid] = mesh_norm[tid];

  if (tid < DIM) {
    // Rebuild _normalize_pdf per block (tiny; amortized over grid-stride loop).
    const int d = tid;
    float ssum = 0.f;
    for (int i = 0; i < ME - 1; ++i) {
      float e = expf(log_p[i * DIM + d]);
      ssum += e * (elmt_size[i] + elmt_size[i + 1]) * 0.5f;
    }
    const float scale = (1.0f - elmt_size[0]) / ssum;
    float F = 0.f;
    float prev = 1.0f;                       // pdf_norm[0] = 1
    for (int j = 0; j < ME; ++j) {
      float cur = (j < ME - 1) ? expf(log_p[j * DIM + d]) * scale : 1.0f;  // pdf_norm[j+1]
      float h = elmt_size[j];
      float C = 0.5f * (cur - prev) / h;
      s_coef[j * 17 + d] = make_float4(F, prev, C, C + C);  // (F_ref, v1, C, 2C)
      F += (prev + cur) * 0.5f * h;          // cumsum(cell)
      prev = cur;
    }
  }
  __syncthreads();

  const int tpg = gridDim.x * blockDim.x;
  const float4* __restrict__ x4 = reinterpret_cast<const float4*>(x);
  float4* __restrict__ out4 = reinterpret_cast<float4*>(out);
  const int np16 = npts * DIM;

  for (int g = blockIdx.x * blockDim.x + tid; g < nquads; g += tpg) {
    const int p = g >> 2;          // point
    const int q = g & 3;           // quad within point (dims q*4..q*4+3)
    const float4 xv = x4[g];
    const float vals[4] = {xv.x, xv.y, xv.z, xv.w};
    float yv[4];
    float prodq = 1.f;

#pragma unroll
    for (int j = 0; j < 4; ++j) {
      const int d = q * 4 + j;
      const float val = vals[j];
      const float xn = (val + BOUNDF) * 0.01f;
      const bool cover = (xn > 0.f) && (xn <= 1.f);   // k!=0 && k!=65

      // analytic bin guess: mesh is geometric, boundaries at integer n
      const float t = fabsf(val);
      const float u = fmaf(t, K1, 1.0f);              // r^j at boundaries
      const float n = __log2f(u) * INV_L2R;
      int k = (val > 0.f) ? (32 + (int)ceilf(n)) : (32 - (int)floorf(n));
      k = imin(imax(k, 1), ME);

      // exact +-1 fixup against the true float32 mesh (matches searchsorted 'left')
      const float m_hi = s_mesh[k];
      const float m_lo = s_mesh[k - 1];
      int km1; float m_b;
      if (xn > m_hi)        { km1 = k;     m_b = m_hi; }
      else if (xn <= m_lo)  { km1 = k - 2; m_b = s_mesh[imax(k - 2, 0)]; }
      else                  { km1 = k - 1; m_b = m_lo; }
      km1 = imin(imax(km1, 0), ME - 1);

      const float4 cf = s_coef[km1 * 17 + d];         // (F_ref, v1, C, 2C)
      const float xm = xn - m_b;
      float y  = fmaf(xm, fmaf(xm, cf.z, cf.y), cf.x);
      float dt = fmaf(xm, cf.w, cf.y);
      y  = cover ? y  : xn;
      dt = cover ? dt : 1.0f;
      yv[j] = fmaf(y, 2.0f * BOUNDF, -BOUNDF);
      prodq *= dt;
    }

    out4[g] = make_float4(yv[0], yv[1], yv[2], yv[3]);

    // reduce across the 4 lanes of this point
    prodq *= __shfl_xor(prodq, 1);
    prodq *= __shfl_xor(prodq, 2);

    if (q == 0) {
      out[np16 + p]        = pdj[p] * prodq;
      out[np16 + npts + p] = sldj[p] + logf(prodq);
    }
  }
}

extern "C" void kernel_launch(void* const* d_in, const int* in_sizes, int n_in,
                              void* d_out, int out_size, void* d_ws, size_t ws_size,
                              hipStream_t stream) {
  const float* x    = (const float*)d_in[0];
  const float* pdj  = (const float*)d_in[1];
  const float* sldj = (const float*)d_in[2];
  const float* lp   = (const float*)d_in[3];
  const float* mesh = (const float*)d_in[4];
  const float* es   = (const float*)d_in[5];
  float* out = (float*)d_out;

  const int npts   = in_sizes[0] / DIM;
  const int nquads = npts * 4;
  const int block  = 256;
  int grid = 2048;                                  // 8 blocks/CU, all resident
  const int needed = (nquads + block - 1) / block;
  if (needed < grid) grid = needed;

  hipLaunchKernelGGL(nll_kernel, dim3(grid), dim3(block), 0, stream,
                     x, pdj, sldj, lp, mesh, es, out, npts, nquads);
}

// Round 2
// 36.074 us; speedup vs baseline: 1.1357x; 1.1357x over previous
//
#include <hip/hip_runtime.h>
#include <math.h>

// NonLinearLayer: piecewise-quadratic CDF flow on a geometric mesh.
// x:(N,16) f32, pdj:(N,1), sldj:(N,1), log_p:(63,16), mesh_norm:(65,), elmt_size:(64,)
// out = concat(x_out (N*16), pdj_out (N), sldj_out (N))

namespace {
constexpr int DIM = 16;    // INPUT_DIM
constexpr int ME  = 64;    // NUM_ELMT
constexpr float BOUNDF = 50.0f;
// mesh constants (MESH_RATIO=1.2, BOUND=50):
//   1.2^32 = 341.8218917..., one_step = 10/(1.2^32-1) = 0.029340416...
//   K1 = 0.2/one_step = 6.8164378..., 1/log2(1.2) = 3.8017840...
constexpr float K1      = 6.8164378f;
constexpr float INV_L2R = 3.8017840f;
// coef region: 64 bins * 68 floats (float4[16] padded to 17) = 4352 floats
constexpr int COEF_FLOATS = ME * 68;           // 4352
constexpr int EP_BASE     = COEF_FLOATS - 63 * DIM;  // 3344: ep scratch in tail
}

__device__ __forceinline__ int imin(int a, int b) { return a < b ? a : b; }
__device__ __forceinline__ int imax(int a, int b) { return a > b ? a : b; }

__global__ __launch_bounds__(256) void nll_kernel(
    const float* __restrict__ x,
    const float* __restrict__ pdj,
    const float* __restrict__ sldj,
    const float* __restrict__ log_p,
    const float* __restrict__ mesh_norm,
    const float* __restrict__ elmt_size,
    float* __restrict__ out,
    int npts, int npairs)
{
  __shared__ __align__(16) float co[COEF_FLOATS];  // coef[bin][dim] as (A,B,D,2A), stride 68 floats
  __shared__ float  s_mesh[ME + 1];
  __shared__ float2 s_pair[ME];        // s_pair[k-1] = (mesh[k-1], mesh[k])
  __shared__ float  s_invh[ME];

  const int tid = threadIdx.x;

  // ---- phase 1: parallel loads + exp ----
  if (tid <= ME) s_mesh[tid] = mesh_norm[tid];
  if (tid >= 128 && tid < 128 + ME) {
    const int j = tid - 128;
    s_invh[j] = 1.0f / (mesh_norm[j + 1] - mesh_norm[j]);
  }
  for (int i = tid; i < 63 * DIM; i += 256)
    co[EP_BASE + i] = __expf(log_p[i]);
  __syncthreads();

  // ---- phase 2: scan (wave 0, 16 lanes) + pair build (wave 1) ----
  if (tid < DIM) {
    const int d = tid;
    float ssum = 0.f;
    for (int j = 0; j < ME - 1; ++j)
      ssum += co[EP_BASE + j * DIM + d] * (s_mesh[j + 2] - s_mesh[j]);
    ssum *= 0.5f;
    const float scale = (1.0f - (s_mesh[1] - s_mesh[0])) / ssum;
    float F = 0.f, prev = 1.0f;
    for (int j = 0; j < ME; ++j) {
      const float cur = (j < ME - 1) ? co[EP_BASE + j * DIM + d] * scale : 1.0f;
      const float m = s_mesh[j];
      const float h = s_mesh[j + 1] - m;
      const float A = 0.5f * (cur - prev) * s_invh[j];
      const float B = fmaf(-2.0f * A, m, prev);
      const float D = fmaf(m, fmaf(m, A, -prev), F);
      *reinterpret_cast<float4*>(&co[j * 68 + 4 * d]) = make_float4(A, B, D, A + A);
      F = fmaf((prev + cur) * 0.5f, h, F);
      prev = cur;
    }
  } else if (tid >= 64 && tid < 64 + ME) {
    const int k = tid - 64;               // 0..63 -> pair for k+1
    s_pair[k] = make_float2(s_mesh[k], s_mesh[k + 1]);
  }
  __syncthreads();

  // ---- main loop: 8 elements (half a point) per thread per iteration ----
  const int tpg = gridDim.x * blockDim.x;
  const float4* __restrict__ x4 = reinterpret_cast<const float4*>(x);
  float4* __restrict__ out4 = reinterpret_cast<float4*>(out);
  const int np16 = npts * DIM;

  for (int t = blockIdx.x * blockDim.x + tid; t < npairs; t += tpg) {
    const int p = t >> 1;              // point
    const int hh = t & 1;              // half: dims hh*8 .. hh*8+7
    const float4 xa = x4[2 * t];
    const float4 xb = x4[2 * t + 1];
    const float vals[8] = {xa.x, xa.y, xa.z, xa.w, xb.x, xb.y, xb.z, xb.w};
    float yv[8];
    float prodq = 1.f;

#pragma unroll
    for (int j = 0; j < 8; ++j) {
      const int d = (hh << 3) + j;
      const float val = vals[j];
      const float xn = (val + BOUNDF) * 0.01f;
      const bool cover = (xn > 0.f) && (xn <= 1.f);

      // analytic bin guess (geometric mesh), exact +-1 fixup below
      const float tt = fabsf(val);
      const float u = fmaf(tt, K1, 1.0f);
      const float n = __log2f(u) * INV_L2R;
      int k = (val > 0.f) ? (32 + (int)ceilf(n)) : (32 - (int)floorf(n));
      k = imin(imax(k, 1), ME);

      const float2 pr = s_pair[k - 1];   // (mesh[k-1], mesh[k])
      int km1 = (k - 1) + (xn > pr.y ? 1 : 0) - (xn <= pr.x ? 1 : 0);
      km1 = imin(imax(km1, 0), ME - 1);

      const float4 cf = *reinterpret_cast<const float4*>(&co[km1 * 68 + 4 * d]); // (A,B,D,2A)
      float y  = fmaf(xn, fmaf(xn, cf.x, cf.y), cf.z);
      float dt = fmaf(xn, cf.w, cf.y);
      y  = cover ? y  : xn;
      dt = cover ? dt : 1.0f;
      yv[j] = fmaf(y, 2.0f * BOUNDF, -BOUNDF);
      prodq *= dt;
    }

    out4[2 * t]     = make_float4(yv[0], yv[1], yv[2], yv[3]);
    out4[2 * t + 1] = make_float4(yv[4], yv[5], yv[6], yv[7]);

    const float other = __shfl_xor(prodq, 1);
    const float full = prodq * other;
    if (hh == 0) out[np16 + p]        = pdj[p] * full;
    else         out[np16 + npts + p] = sldj[p] + __logf(full);
  }
}

extern "C" void kernel_launch(void* const* d_in, const int* in_sizes, int n_in,
                              void* d_out, int out_size, void* d_ws, size_t ws_size,
                              hipStream_t stream) {
  const float* x    = (const float*)d_in[0];
  const float* pdj  = (const float*)d_in[1];
  const float* sldj = (const float*)d_in[2];
  const float* lp   = (const float*)d_in[3];
  const float* mesh = (const float*)d_in[4];
  const float* es   = (const float*)d_in[5];
  float* out = (float*)d_out;

  const int npts   = in_sizes[0] / DIM;
  const int npairs = npts * 2;
  const int block  = 256;
  int grid = 2048;
  const int needed = (npairs + block - 1) / block;
  if (needed < grid) grid = needed;

  hipLaunchKernelGGL(nll_kernel, dim3(grid), dim3(block), 0, stream,
                     x, pdj, sldj, lp, mesh, es, out, npts, npairs);
}